// Round 2
// baseline (477.391 us; speedup 1.0000x reference)
//
#include <hip/hip_runtime.h>

// PerturbedTopK: x(32,2048) f32, noise(32,500,2048) f32.
// out = [indicators (32,128,2048) f32, idx (32,500,128) as f32], concatenated.
//
// R2: candidate pruning. Kernel 1 computes per-b cutoff key (128th largest of
// x_b minus margin). Kernel 2: one wave per (b,n) row; candidates = keys >= ck
// (mean ~191 of 2048, exact-correct whenever C >= 128); compact into LDS;
// 32-pass bitwise radix select over 4 slots/lane with scalar ballot counting
// (no ds_swizzle chains); ballot-ranked emission. Tails -> verified R1 path.

constexpr int B_     = 32;
constexpr int D_     = 2048;
constexpr int NS_    = 500;
constexpr int TOPK_  = 128;
constexpr float SIGMA_  = 0.05f;
constexpr float MARGIN_ = 0.25f;
constexpr int PER_LANE_ = D_ / 64;       // 32
constexpr int WAVES_PER_BLOCK_ = 4;
constexpr int CAP_   = 256;              // fast-path candidate cap (4 slots)
constexpr int SLOTS_ = CAP_ / 64;        // 4

__device__ __forceinline__ uint32_t order_key(float f) {
  uint32_t u = __float_as_uint(f);
  return (u & 0x80000000u) ? ~u : (u | 0x80000000u);
}
__device__ __forceinline__ float inv_key(uint32_t k) {
  uint32_t u = (k & 0x80000000u) ? (k & 0x7FFFFFFFu) : ~k;
  return __uint_as_float(u);
}

// ---- kernel 1: per-b cutoff key (exact 128th largest of x_b, minus margin) ----
__global__ __launch_bounds__(64) void ptk_cutoff(const float* __restrict__ x,
                                                 uint32_t* __restrict__ ckey) {
  const int lane = threadIdx.x & 63;
  const int b = blockIdx.x;
  const float* __restrict__ xr = x + (size_t)b * D_;
  uint32_t keys[PER_LANE_];
#pragma unroll
  for (int j = 0; j < PER_LANE_; j += 4) {
    const float4 xv = *reinterpret_cast<const float4*>(xr + lane * PER_LANE_ + j);
    keys[j + 0] = order_key(xv.x); keys[j + 1] = order_key(xv.y);
    keys[j + 2] = order_key(xv.z); keys[j + 3] = order_key(xv.w);
  }
  uint32_t prefix = 0; int k = TOPK_;
#pragma unroll 1
  for (int bit = 31; bit >= 0; --bit) {
    const uint32_t want = (prefix >> bit) | 1u;
    int c = 0;
#pragma unroll
    for (int j = 0; j < PER_LANE_; ++j) c += ((keys[j] >> bit) == want) ? 1 : 0;
#pragma unroll
    for (int off = 32; off >= 1; off >>= 1) c += __shfl_xor(c, off);
    if (c >= k) prefix |= (1u << bit); else k -= c;
  }
  if (lane == 0) ckey[b] = order_key(inv_key(prefix) - MARGIN_);
}

// ---- kernel 2: main ----
__global__ __launch_bounds__(256) void ptk_select(
    const float* __restrict__ x, const float* __restrict__ noise,
    const uint32_t* __restrict__ ckey,
    float* __restrict__ indicators, float* __restrict__ out_idx) {
  __shared__ uint2 comp[WAVES_PER_BLOCK_][CAP_];

  const int lane = threadIdx.x & 63;
  const int wave = threadIdx.x >> 6;
  const int row  = blockIdx.x * WAVES_PER_BLOCK_ + wave;   // 0..15999
  const int b = row / NS_;
  const int n = row - b * NS_;

  const float* __restrict__ xr = x + (size_t)b * D_;
  const float* __restrict__ nr = noise + ((size_t)b * NS_ + n) * D_;
  const int base_i = lane * PER_LANE_;

  uint32_t keys[PER_LANE_];
#pragma unroll
  for (int j = 0; j < PER_LANE_; j += 4) {
    const float4 nv = *reinterpret_cast<const float4*>(nr + base_i + j);
    const float4 xv = *reinterpret_cast<const float4*>(xr + base_i + j);
    keys[j + 0] = order_key(fmaf(SIGMA_, nv.x, xv.x));
    keys[j + 1] = order_key(fmaf(SIGMA_, nv.y, xv.y));
    keys[j + 2] = order_key(fmaf(SIGMA_, nv.z, xv.z));
    keys[j + 3] = order_key(fmaf(SIGMA_, nv.w, xv.w));
  }

  const uint32_t ck = ckey[b];   // wave-uniform

  // candidate mask + count + wave exclusive scan
  uint32_t m = 0;
#pragma unroll
  for (int j = 0; j < PER_LANE_; ++j) m |= (keys[j] >= ck) ? (1u << j) : 0u;
  const int cnt = __popc(m);
  int incl = cnt;
#pragma unroll
  for (int off = 1; off < 64; off <<= 1) {
    int y = __shfl_up(incl, (unsigned)off);
    if (lane >= off) incl += y;
  }
  const int offset = incl - cnt;
  const int C = __shfl(incl, 63);   // wave-uniform total

  float* __restrict__ ind_b   = indicators + (size_t)b * TOPK_ * D_;
  float* __restrict__ idx_row = out_idx + (size_t)row * TOPK_;
  const float inc = 1.0f / (float)NS_;

  if (C >= TOPK_ && C <= CAP_) {
    // ---------- fast path ----------
    // compact (key, idx) ascending by index into LDS
    {
      uint32_t mm = m; int p = offset;
      while (mm) {
        const int j = __ffs(mm) - 1; mm &= mm - 1;
        comp[wave][p] = make_uint2(keys[j], (uint32_t)(base_i + j));
        ++p;
      }
    }
    __asm__ volatile("s_waitcnt lgkmcnt(0)" ::: "memory");

    uint32_t kk[SLOTS_], ki[SLOTS_];
#pragma unroll
    for (int s = 0; s < SLOTS_; ++s) {
      const int p = (s << 6) + lane;
      const uint2 v = (p < C) ? comp[wave][p] : make_uint2(0u, 0u);
      kk[s] = v.x; ki[s] = v.y;   // pad key 0 can never match/win (real keys > 0)
    }

    // bitwise radix select with scalar ballot counting (no shuffle chains)
    uint32_t prefix = 0; int k = TOPK_;
#pragma unroll 1
    for (int bit = 31; bit >= 0; --bit) {
      const uint32_t want = (prefix >> bit) | 1u;
      int c = 0;
#pragma unroll
      for (int s = 0; s < SLOTS_; ++s)
        c += __popcll(__ballot((kk[s] >> bit) == want));
      if (c >= k) prefix |= (1u << bit); else k -= c;
    }
    const int r = k;  // ties at prefix to take, lowest index first

    // ballot-ranked emission, ascending index order
    const uint64_t below = (lane == 0) ? 0ull : ((~0ull) >> (64 - lane));
    int sel_run = 0, eq_run = 0;
#pragma unroll
    for (int s = 0; s < SLOTS_; ++s) {
      const bool gt = kk[s] > prefix;
      const bool eq = kk[s] == prefix;
      const uint64_t meq = __ballot(eq);
      const int eqrank = eq_run + __popcll(meq & below);
      const bool sel = gt || (eq && (eqrank < r));
      const uint64_t msel = __ballot(sel);
      if (sel) {
        const int pos = sel_run + __popcll(msel & below);
        const int i = (int)ki[s];
        idx_row[pos] = (float)i;
        atomicAdd(ind_b + (size_t)pos * D_ + i, inc);
      }
      sel_run += __popcll(msel);
      eq_run  += __popcll(meq);
    }
  } else {
    // ---------- fallback: verified R1 path (C<128 impossible-slack / C>CAP) ----------
    uint32_t prefix = 0; int k = TOPK_;
#pragma unroll 1
    for (int bit = 31; bit >= 0; --bit) {
      const uint32_t want = (prefix >> bit) | 1u;
      int c = 0;
#pragma unroll
      for (int j = 0; j < PER_LANE_; ++j) c += ((keys[j] >> bit) == want) ? 1 : 0;
#pragma unroll
      for (int off = 32; off >= 1; off >>= 1) c += __shfl_xor(c, off);
      if (c >= k) prefix |= (1u << bit); else k -= c;
    }
    const int r = k;

    int gt = 0, eq = 0;
#pragma unroll
    for (int j = 0; j < PER_LANE_; ++j) {
      gt += (keys[j] > prefix) ? 1 : 0;
      eq += (keys[j] == prefix) ? 1 : 0;
    }
    uint32_t incl2 = (uint32_t)gt | ((uint32_t)eq << 16);
#pragma unroll
    for (int off = 1; off < 64; off <<= 1) {
      uint32_t y = __shfl_up(incl2, (unsigned)off);
      if (lane >= off) incl2 += y;
    }
    const int gt_base = (int)(incl2 & 0xFFFFu) - gt;
    const int eq_base = (int)(incl2 >> 16) - eq;
    int pos = gt_base + min(eq_base, r);
    int eq_seen = eq_base;
#pragma unroll
    for (int j = 0; j < PER_LANE_; ++j) {
      const uint32_t kj = keys[j];
      bool s = false;
      if (kj > prefix) s = true;
      else if (kj == prefix) { s = (eq_seen < r); eq_seen++; }
      if (s) {
        const int i = base_i + j;
        idx_row[pos] = (float)i;
        atomicAdd(ind_b + (size_t)pos * D_ + i, inc);
        pos++;
      }
    }
  }
}

extern "C" void kernel_launch(void* const* d_in, const int* in_sizes, int n_in,
                              void* d_out, int out_size, void* d_ws, size_t ws_size,
                              hipStream_t stream) {
  const float* x     = (const float*)d_in[0];
  const float* noise = (const float*)d_in[1];
  float* indicators  = (float*)d_out;
  float* out_idx     = (float*)d_out + (size_t)B_ * TOPK_ * D_;
  uint32_t* ckey     = (uint32_t*)d_ws;

  hipMemsetAsync(d_out, 0, (size_t)B_ * TOPK_ * D_ * sizeof(float), stream);
  hipLaunchKernelGGL(ptk_cutoff, dim3(B_), dim3(64), 0, stream, x, ckey);

  const int rows = B_ * NS_;                        // 16000
  dim3 grid(rows / WAVES_PER_BLOCK_), block(256);   // 4000 x 256
  hipLaunchKernelGGL(ptk_select, grid, block, 0, stream,
                     x, noise, ckey, indicators, out_idx);
}

// Round 3
// 249.623 us; speedup vs baseline: 1.9124x; 1.9124x over previous
//
#include <hip/hip_runtime.h>

// PerturbedTopK: x(32,2048) f32, noise(32,500,2048) f32.
// out = [indicators (32,128,2048) f32, idx (32,500,128) as f32], concatenated.
//
// R3: no global atomics. Phase 1: one wave per (b,n) row; candidate pruning
// vs per-b cutoff; ballot radix select; writes ONLY idx (coalesced).
// Phase 2: histogram kernel — block per (b, 8-rank chunk), 8x2048-bin LDS
// histograms over the 500 samples, writes all of indicators (so no memset).

constexpr int B_     = 32;
constexpr int D_     = 2048;
constexpr int NS_    = 500;
constexpr int TOPK_  = 128;
constexpr float SIGMA_  = 0.05f;
constexpr float MARGIN_ = 0.25f;
constexpr int PER_LANE_ = D_ / 64;       // 32
constexpr int WAVES_PER_BLOCK_ = 4;      // 500 % 4 == 0 -> all waves in a block share b
constexpr int CAP_   = 256;              // fast-path candidate cap (4 slots)
constexpr int SLOTS_ = CAP_ / 64;        // 4
constexpr int JCHUNK_ = 8;               // ranks per phase-2 block

__device__ __forceinline__ uint32_t order_key(float f) {
  uint32_t u = __float_as_uint(f);
  return (u & 0x80000000u) ? ~u : (u | 0x80000000u);
}
__device__ __forceinline__ float inv_key(uint32_t k) {
  uint32_t u = (k & 0x80000000u) ? (k & 0x7FFFFFFFu) : ~k;
  return __uint_as_float(u);
}

// ---- kernel 1: per-b cutoff key (exact 128th largest of x_b, minus margin) ----
__global__ __launch_bounds__(64) void ptk_cutoff(const float* __restrict__ x,
                                                 uint32_t* __restrict__ ckey) {
  const int lane = threadIdx.x & 63;
  const int b = blockIdx.x;
  const float* __restrict__ xr = x + (size_t)b * D_;
  uint32_t keys[PER_LANE_];
#pragma unroll
  for (int j = 0; j < PER_LANE_; j += 4) {
    const float4 xv = *reinterpret_cast<const float4*>(xr + lane * PER_LANE_ + j);
    keys[j + 0] = order_key(xv.x); keys[j + 1] = order_key(xv.y);
    keys[j + 2] = order_key(xv.z); keys[j + 3] = order_key(xv.w);
  }
  uint32_t prefix = 0; int k = TOPK_;
#pragma unroll 1
  for (int bit = 31; bit >= 0; --bit) {
    const uint32_t want = (prefix >> bit) | 1u;
    int c = 0;
#pragma unroll
    for (int j = 0; j < PER_LANE_; ++j) c += ((keys[j] >> bit) == want) ? 1 : 0;
#pragma unroll
    for (int off = 32; off >= 1; off >>= 1) c += __shfl_xor(c, off);
    if (c >= k) prefix |= (1u << bit); else k -= c;
  }
  if (lane == 0) ckey[b] = order_key(inv_key(prefix) - MARGIN_);
}

// ---- kernel 2: selection, writes idx only ----
__global__ __launch_bounds__(256) void ptk_select(
    const float* __restrict__ x, const float* __restrict__ noise,
    const uint32_t* __restrict__ ckey, float* __restrict__ out_idx) {
  __shared__ uint2 comp[WAVES_PER_BLOCK_][CAP_];

  const int lane = threadIdx.x & 63;
  const int wave = threadIdx.x >> 6;
  const int row  = blockIdx.x * WAVES_PER_BLOCK_ + wave;   // 0..15999
  const int b = row / NS_;
  const int n = row - b * NS_;

  const float* __restrict__ xr = x + (size_t)b * D_;
  const float* __restrict__ nr = noise + ((size_t)b * NS_ + n) * D_;
  const int base_i = lane * PER_LANE_;

  uint32_t keys[PER_LANE_];
#pragma unroll
  for (int j = 0; j < PER_LANE_; j += 4) {
    const float4 nv = *reinterpret_cast<const float4*>(nr + base_i + j);
    const float4 xv = *reinterpret_cast<const float4*>(xr + base_i + j);
    keys[j + 0] = order_key(fmaf(SIGMA_, nv.x, xv.x));
    keys[j + 1] = order_key(fmaf(SIGMA_, nv.y, xv.y));
    keys[j + 2] = order_key(fmaf(SIGMA_, nv.z, xv.z));
    keys[j + 3] = order_key(fmaf(SIGMA_, nv.w, xv.w));
  }

  const uint32_t ck = ckey[b];   // wave-uniform

  uint32_t m = 0;
#pragma unroll
  for (int j = 0; j < PER_LANE_; ++j) m |= (keys[j] >= ck) ? (1u << j) : 0u;
  const int cnt = __popc(m);
  int incl = cnt;
#pragma unroll
  for (int off = 1; off < 64; off <<= 1) {
    int y = __shfl_up(incl, (unsigned)off);
    if (lane >= off) incl += y;
  }
  const int offset = incl - cnt;
  const int C = __shfl(incl, 63);

  float* __restrict__ idx_row = out_idx + (size_t)row * TOPK_;

  if (C >= TOPK_ && C <= CAP_) {
    // ---------- fast path ----------
    {
      uint32_t mm = m; int p = offset;
      while (mm) {
        const int j = __ffs(mm) - 1; mm &= mm - 1;
        comp[wave][p] = make_uint2(keys[j], (uint32_t)(base_i + j));
        ++p;
      }
    }
    __asm__ volatile("s_waitcnt lgkmcnt(0)" ::: "memory");

    uint32_t kk[SLOTS_], ki[SLOTS_];
#pragma unroll
    for (int s = 0; s < SLOTS_; ++s) {
      const int p = (s << 6) + lane;
      const uint2 v = (p < C) ? comp[wave][p] : make_uint2(0u, 0u);
      kk[s] = v.x; ki[s] = v.y;   // pad key 0 never selected (real keys > 0)
    }

    uint32_t prefix = 0; int k = TOPK_;
#pragma unroll 1
    for (int bit = 31; bit >= 0; --bit) {
      const uint32_t want = (prefix >> bit) | 1u;
      int c = 0;
#pragma unroll
      for (int s = 0; s < SLOTS_; ++s)
        c += __popcll(__ballot((kk[s] >> bit) == want));
      if (c >= k) prefix |= (1u << bit); else k -= c;
    }
    const int r = k;

    const uint64_t below = (lane == 0) ? 0ull : ((~0ull) >> (64 - lane));
    int sel_run = 0, eq_run = 0;
#pragma unroll
    for (int s = 0; s < SLOTS_; ++s) {
      const bool gt = kk[s] > prefix;
      const bool eq = kk[s] == prefix;
      const uint64_t meq = __ballot(eq);
      const int eqrank = eq_run + __popcll(meq & below);
      const bool sel = gt || (eq && (eqrank < r));
      const uint64_t msel = __ballot(sel);
      if (sel) {
        const int pos = sel_run + __popcll(msel & below);
        idx_row[pos] = (float)(int)ki[s];
      }
      sel_run += __popcll(msel);
      eq_run  += __popcll(meq);
    }
  } else {
    // ---------- fallback (rare): exact select over all 2048 ----------
    uint32_t prefix = 0; int k = TOPK_;
#pragma unroll 1
    for (int bit = 31; bit >= 0; --bit) {
      const uint32_t want = (prefix >> bit) | 1u;
      int c = 0;
#pragma unroll
      for (int j = 0; j < PER_LANE_; ++j) c += ((keys[j] >> bit) == want) ? 1 : 0;
#pragma unroll
      for (int off = 32; off >= 1; off >>= 1) c += __shfl_xor(c, off);
      if (c >= k) prefix |= (1u << bit); else k -= c;
    }
    const int r = k;

    int gt = 0, eq = 0;
#pragma unroll
    for (int j = 0; j < PER_LANE_; ++j) {
      gt += (keys[j] > prefix) ? 1 : 0;
      eq += (keys[j] == prefix) ? 1 : 0;
    }
    uint32_t incl2 = (uint32_t)gt | ((uint32_t)eq << 16);
#pragma unroll
    for (int off = 1; off < 64; off <<= 1) {
      uint32_t y = __shfl_up(incl2, (unsigned)off);
      if (lane >= off) incl2 += y;
    }
    const int gt_base = (int)(incl2 & 0xFFFFu) - gt;
    const int eq_base = (int)(incl2 >> 16) - eq;
    int pos = gt_base + min(eq_base, r);
    int eq_seen = eq_base;
#pragma unroll
    for (int j = 0; j < PER_LANE_; ++j) {
      const uint32_t kj = keys[j];
      bool s = false;
      if (kj > prefix) s = true;
      else if (kj == prefix) { s = (eq_seen < r); eq_seen++; }
      if (s) { idx_row[pos] = (float)(base_i + j); pos++; }
    }
  }
}

// ---- kernel 3: histograms -> indicators (writes every element; no memset) ----
__global__ __launch_bounds__(256) void ptk_hist(
    const float* __restrict__ out_idx, float* __restrict__ indicators) {
  __shared__ int hist[JCHUNK_][D_];   // 64 KB

  const int tid   = threadIdx.x;
  const int b     = blockIdx.x >> 4;         // 16 chunks per b
  const int chunk = blockIdx.x & 15;
  const int j0    = chunk * JCHUNK_;

  for (int t = tid; t < JCHUNK_ * D_; t += 256)
    ((int*)hist)[t] = 0;
  __syncthreads();

  const float* __restrict__ src = out_idx + (size_t)b * NS_ * TOPK_ + j0;
  for (int t = tid; t < NS_ * JCHUNK_; t += 256) {
    const int jj = t & (JCHUNK_ - 1);
    const int n  = t >> 3;
    const int v  = (int)src[(size_t)n * TOPK_ + jj];
    atomicAdd(&hist[jj][v], 1);
  }
  __syncthreads();

  float* __restrict__ dst = indicators + ((size_t)b * TOPK_ + j0) * D_;
  for (int t = tid; t < JCHUNK_ * D_; t += 256)
    dst[t] = (float)((int*)hist)[t] / (float)NS_;
}

extern "C" void kernel_launch(void* const* d_in, const int* in_sizes, int n_in,
                              void* d_out, int out_size, void* d_ws, size_t ws_size,
                              hipStream_t stream) {
  const float* x     = (const float*)d_in[0];
  const float* noise = (const float*)d_in[1];
  float* indicators  = (float*)d_out;
  float* out_idx     = (float*)d_out + (size_t)B_ * TOPK_ * D_;
  uint32_t* ckey     = (uint32_t*)d_ws;

  hipLaunchKernelGGL(ptk_cutoff, dim3(B_), dim3(64), 0, stream, x, ckey);

  const int rows = B_ * NS_;                        // 16000
  hipLaunchKernelGGL(ptk_select, dim3(rows / WAVES_PER_BLOCK_), dim3(256), 0,
                     stream, x, noise, ckey, out_idx);

  hipLaunchKernelGGL(ptk_hist, dim3(B_ * 16), dim3(256), 0, stream,
                     out_idx, indicators);
}

// Round 4
// 238.110 us; speedup vs baseline: 2.0049x; 1.0484x over previous
//
#include <hip/hip_runtime.h>

// PerturbedTopK: x(32,2048) f32, noise(32,500,2048) f32.
// out = [indicators (32,128,2048) f32, idx (32,500,128) as f32], concatenated.
//
// R4: lazy order_key (float-domain candidate mask; keys only for ~191
// candidates at LDS-compact time), dynamic skip of the sign radix pass,
// float4-vectorized histogram kernel. Structure from R3: select writes idx
// only (no atomics); hist rebuilds indicators from idx via LDS histograms.

constexpr int B_     = 32;
constexpr int D_     = 2048;
constexpr int NS_    = 500;
constexpr int TOPK_  = 128;
constexpr float SIGMA_  = 0.05f;
constexpr float MARGIN_ = 0.25f;
constexpr int PER_LANE_ = D_ / 64;       // 32
constexpr int WAVES_PER_BLOCK_ = 4;
constexpr int CAP_   = 256;              // fast-path candidate cap (4 slots)
constexpr int SLOTS_ = CAP_ / 64;        // 4
constexpr int JCHUNK_ = 8;               // ranks per hist block

__device__ __forceinline__ uint32_t order_key(float f) {
  uint32_t u = __float_as_uint(f);
  return (u & 0x80000000u) ? ~u : (u | 0x80000000u);
}
__device__ __forceinline__ float inv_key(uint32_t k) {
  uint32_t u = (k & 0x80000000u) ? (k & 0x7FFFFFFFu) : ~k;
  return __uint_as_float(u);
}

// ---- kernel 1: per-b float cutoff (exact 128th largest of x_b, minus margin) ----
__global__ __launch_bounds__(64) void ptk_cutoff(const float* __restrict__ x,
                                                 float* __restrict__ cutf) {
  const int lane = threadIdx.x & 63;
  const int b = blockIdx.x;
  const float* __restrict__ xr = x + (size_t)b * D_;
  uint32_t keys[PER_LANE_];
#pragma unroll
  for (int j = 0; j < PER_LANE_; j += 4) {
    const float4 xv = *reinterpret_cast<const float4*>(xr + lane * PER_LANE_ + j);
    keys[j + 0] = order_key(xv.x); keys[j + 1] = order_key(xv.y);
    keys[j + 2] = order_key(xv.z); keys[j + 3] = order_key(xv.w);
  }
  uint32_t prefix = 0; int k = TOPK_;
#pragma unroll 1
  for (int bit = 31; bit >= 0; --bit) {
    const uint32_t want = (prefix >> bit) | 1u;
    int c = 0;
#pragma unroll
    for (int j = 0; j < PER_LANE_; ++j) c += ((keys[j] >> bit) == want) ? 1 : 0;
#pragma unroll
    for (int off = 32; off >= 1; off >>= 1) c += __shfl_xor(c, off);
    if (c >= k) prefix |= (1u << bit); else k -= c;
  }
  if (lane == 0) cutf[b] = inv_key(prefix) - MARGIN_;
}

// ---- kernel 2: selection, writes idx only ----
__global__ __launch_bounds__(256) void ptk_select(
    const float* __restrict__ x, const float* __restrict__ noise,
    const float* __restrict__ cutf, float* __restrict__ out_idx) {
  __shared__ uint2 comp[WAVES_PER_BLOCK_][CAP_];

  const int lane = threadIdx.x & 63;
  const int wave = threadIdx.x >> 6;
  const int row  = blockIdx.x * WAVES_PER_BLOCK_ + wave;   // 0..15999
  const int b = row / NS_;
  const int n = row - b * NS_;

  const float* __restrict__ xr = x + (size_t)b * D_;
  const float* __restrict__ nr = noise + ((size_t)b * NS_ + n) * D_;
  const int base_i = lane * PER_LANE_;

  float p[PER_LANE_];
#pragma unroll
  for (int j = 0; j < PER_LANE_; j += 4) {
    const float4 nv = *reinterpret_cast<const float4*>(nr + base_i + j);
    const float4 xv = *reinterpret_cast<const float4*>(xr + base_i + j);
    p[j + 0] = fmaf(SIGMA_, nv.x, xv.x);
    p[j + 1] = fmaf(SIGMA_, nv.y, xv.y);
    p[j + 2] = fmaf(SIGMA_, nv.z, xv.z);
    p[j + 3] = fmaf(SIGMA_, nv.w, xv.w);
  }

  const float cf = cutf[b];   // wave-uniform

  // candidate mask in float domain (monotone-equivalent to key >= order_key(cf))
  uint32_t m = 0;
#pragma unroll
  for (int j = 0; j < PER_LANE_; ++j) m |= (p[j] >= cf) ? (1u << j) : 0u;
  const int cnt = __popc(m);
  int incl = cnt;
#pragma unroll
  for (int off = 1; off < 64; off <<= 1) {
    int y = __shfl_up(incl, (unsigned)off);
    if (lane >= off) incl += y;
  }
  const int offset = incl - cnt;
  const int C = __shfl(incl, 63);

  float* __restrict__ idx_row = out_idx + (size_t)row * TOPK_;

  if (C >= TOPK_ && C <= CAP_) {
    // ---------- fast path ----------
    {
      uint32_t mm = m; int q = offset;
      while (mm) {
        const int j = __ffs(mm) - 1; mm &= mm - 1;
        comp[wave][q] = make_uint2(order_key(p[j]), (uint32_t)(base_i + j));
        ++q;
      }
    }
    __asm__ volatile("s_waitcnt lgkmcnt(0)" ::: "memory");

    uint32_t kk[SLOTS_], ki[SLOTS_];
#pragma unroll
    for (int s = 0; s < SLOTS_; ++s) {
      const int q = (s << 6) + lane;
      const uint2 v = (q < C) ? comp[wave][q] : make_uint2(0u, 0u);
      kk[s] = v.x; ki[s] = v.y;   // pad key 0 never selected (candidate keys >= key(cf) > 0 region handled by count)
    }

    // bitwise radix select, scalar ballot counting; skip sign pass if cf >= 0
    uint32_t prefix; int startbit;
    if (order_key(cf) & 0x80000000u) { prefix = 0x80000000u; startbit = 30; }
    else                             { prefix = 0u;          startbit = 31; }
    int k = TOPK_;
#pragma unroll 1
    for (int bit = startbit; bit >= 0; --bit) {
      const uint32_t want = (prefix >> bit) | 1u;
      int c = 0;
#pragma unroll
      for (int s = 0; s < SLOTS_; ++s)
        c += __popcll(__ballot((kk[s] >> bit) == want));
      if (c >= k) prefix |= (1u << bit); else k -= c;
    }
    const int r = k;

    const uint64_t below = (lane == 0) ? 0ull : ((~0ull) >> (64 - lane));
    int sel_run = 0, eq_run = 0;
#pragma unroll
    for (int s = 0; s < SLOTS_; ++s) {
      const bool gt = kk[s] > prefix;
      const bool eq = kk[s] == prefix;
      const uint64_t meq = __ballot(eq);
      const int eqrank = eq_run + __popcll(meq & below);
      const bool sel = gt || (eq && (eqrank < r));
      const uint64_t msel = __ballot(sel);
      if (sel) {
        const int pos = sel_run + __popcll(msel & below);
        idx_row[pos] = (float)(int)ki[s];
      }
      sel_run += __popcll(msel);
      eq_run  += __popcll(meq);
    }
  } else {
    // ---------- fallback (rare): exact select over all 2048 ----------
    uint32_t keys[PER_LANE_];
#pragma unroll
    for (int j = 0; j < PER_LANE_; ++j) keys[j] = order_key(p[j]);

    uint32_t prefix = 0; int k = TOPK_;
#pragma unroll 1
    for (int bit = 31; bit >= 0; --bit) {
      const uint32_t want = (prefix >> bit) | 1u;
      int c = 0;
#pragma unroll
      for (int j = 0; j < PER_LANE_; ++j) c += ((keys[j] >> bit) == want) ? 1 : 0;
#pragma unroll
      for (int off = 32; off >= 1; off >>= 1) c += __shfl_xor(c, off);
      if (c >= k) prefix |= (1u << bit); else k -= c;
    }
    const int r = k;

    int gt = 0, eq = 0;
#pragma unroll
    for (int j = 0; j < PER_LANE_; ++j) {
      gt += (keys[j] > prefix) ? 1 : 0;
      eq += (keys[j] == prefix) ? 1 : 0;
    }
    uint32_t incl2 = (uint32_t)gt | ((uint32_t)eq << 16);
#pragma unroll
    for (int off = 1; off < 64; off <<= 1) {
      uint32_t y = __shfl_up(incl2, (unsigned)off);
      if (lane >= off) incl2 += y;
    }
    const int gt_base = (int)(incl2 & 0xFFFFu) - gt;
    const int eq_base = (int)(incl2 >> 16) - eq;
    int pos = gt_base + min(eq_base, r);
    int eq_seen = eq_base;
#pragma unroll
    for (int j = 0; j < PER_LANE_; ++j) {
      const uint32_t kj = keys[j];
      bool s = false;
      if (kj > prefix) s = true;
      else if (kj == prefix) { s = (eq_seen < r); eq_seen++; }
      if (s) { idx_row[pos] = (float)(base_i + j); pos++; }
    }
  }
}

// ---- kernel 3: histograms -> indicators (writes every element; no memset) ----
__global__ __launch_bounds__(256) void ptk_hist(
    const float* __restrict__ out_idx, float* __restrict__ indicators) {
  __shared__ int hist[JCHUNK_][D_];   // 64 KB

  const int tid   = threadIdx.x;
  const int b     = blockIdx.x >> 4;         // 16 chunks per b
  const int chunk = blockIdx.x & 15;
  const int j0    = chunk * JCHUNK_;

  int4* h4 = (int4*)hist;
  for (int t = tid; t < JCHUNK_ * D_ / 4; t += 256)
    h4[t] = make_int4(0, 0, 0, 0);
  __syncthreads();

  const float* __restrict__ src = out_idx + (size_t)b * NS_ * TOPK_ + j0;
  for (int t = tid; t < NS_ * 2; t += 256) {     // 2 float4 per sample (8 ranks)
    const int n = t >> 1;
    const int q = (t & 1) << 2;
    const float4 v = *reinterpret_cast<const float4*>(src + (size_t)n * TOPK_ + q);
    atomicAdd(&hist[q + 0][(int)v.x], 1);
    atomicAdd(&hist[q + 1][(int)v.y], 1);
    atomicAdd(&hist[q + 2][(int)v.z], 1);
    atomicAdd(&hist[q + 3][(int)v.w], 1);
  }
  __syncthreads();

  float4* __restrict__ dst =
      (float4*)(indicators + ((size_t)b * TOPK_ + j0) * D_);
  for (int t = tid; t < JCHUNK_ * D_ / 4; t += 256) {
    const int4 h = h4[t];
    float4 o;
    o.x = (float)h.x / (float)NS_;
    o.y = (float)h.y / (float)NS_;
    o.z = (float)h.z / (float)NS_;
    o.w = (float)h.w / (float)NS_;
    dst[t] = o;
  }
}

extern "C" void kernel_launch(void* const* d_in, const int* in_sizes, int n_in,
                              void* d_out, int out_size, void* d_ws, size_t ws_size,
                              hipStream_t stream) {
  const float* x     = (const float*)d_in[0];
  const float* noise = (const float*)d_in[1];
  float* indicators  = (float*)d_out;
  float* out_idx     = (float*)d_out + (size_t)B_ * TOPK_ * D_;
  float* cutf        = (float*)d_ws;

  hipLaunchKernelGGL(ptk_cutoff, dim3(B_), dim3(64), 0, stream, x, cutf);

  const int rows = B_ * NS_;                        // 16000
  hipLaunchKernelGGL(ptk_select, dim3(rows / WAVES_PER_BLOCK_), dim3(256), 0,
                     stream, x, noise, cutf, out_idx);

  hipLaunchKernelGGL(ptk_hist, dim3(B_ * 16), dim3(256), 0, stream,
                     out_idx, indicators);
}

// Round 5
// 234.868 us; speedup vs baseline: 2.0326x; 1.0138x over previous
//
#include <hip/hip_runtime.h>

// PerturbedTopK: x(32,2048) f32, noise(32,500,2048) f32.
// out = [indicators (32,128,2048) f32, idx (32,500,128) as f32], concatenated.
//
// R5: shorter serial chains in select. Common-prefix skip (and/or reduce),
// early-exit radix (break when active class == 1, broadcast the key),
// ballot-based scan instead of shfl_up. Structure from R3/R4: select writes
// idx only; hist rebuilds indicators from idx via LDS histograms (no memset,
// no global atomics).

constexpr int B_     = 32;
constexpr int D_     = 2048;
constexpr int NS_    = 500;
constexpr int TOPK_  = 128;
constexpr float SIGMA_  = 0.05f;
constexpr float MARGIN_ = 0.25f;
constexpr int PER_LANE_ = D_ / 64;       // 32
constexpr int WAVES_PER_BLOCK_ = 4;
constexpr int CAP_   = 256;              // fast-path candidate cap (4 slots)
constexpr int SLOTS_ = CAP_ / 64;        // 4
constexpr int JCHUNK_ = 8;               // ranks per hist block

__device__ __forceinline__ uint32_t order_key(float f) {
  uint32_t u = __float_as_uint(f);
  return (u & 0x80000000u) ? ~u : (u | 0x80000000u);
}
__device__ __forceinline__ float inv_key(uint32_t k) {
  uint32_t u = (k & 0x80000000u) ? (k & 0x7FFFFFFFu) : ~k;
  return __uint_as_float(u);
}

// ---- kernel 1: per-b float cutoff (exact 128th largest of x_b, minus margin) ----
__global__ __launch_bounds__(64) void ptk_cutoff(const float* __restrict__ x,
                                                 float* __restrict__ cutf) {
  const int lane = threadIdx.x & 63;
  const int b = blockIdx.x;
  const float* __restrict__ xr = x + (size_t)b * D_;
  uint32_t keys[PER_LANE_];
#pragma unroll
  for (int j = 0; j < PER_LANE_; j += 4) {
    const float4 xv = *reinterpret_cast<const float4*>(xr + lane * PER_LANE_ + j);
    keys[j + 0] = order_key(xv.x); keys[j + 1] = order_key(xv.y);
    keys[j + 2] = order_key(xv.z); keys[j + 3] = order_key(xv.w);
  }
  uint32_t prefix = 0; int k = TOPK_;
#pragma unroll 1
  for (int bit = 31; bit >= 0; --bit) {
    const uint32_t want = (prefix >> bit) | 1u;
    int c = 0;
#pragma unroll
    for (int j = 0; j < PER_LANE_; ++j) c += ((keys[j] >> bit) == want) ? 1 : 0;
#pragma unroll
    for (int off = 32; off >= 1; off >>= 1) c += __shfl_xor(c, off);
    if (c >= k) prefix |= (1u << bit); else k -= c;
  }
  if (lane == 0) cutf[b] = inv_key(prefix) - MARGIN_;
}

// ---- kernel 2: selection, writes idx only ----
__global__ __launch_bounds__(256) void ptk_select(
    const float* __restrict__ x, const float* __restrict__ noise,
    const float* __restrict__ cutf, float* __restrict__ out_idx) {
  __shared__ uint2 comp[WAVES_PER_BLOCK_][CAP_];

  const int lane = threadIdx.x & 63;
  const int wave = threadIdx.x >> 6;
  const int row  = blockIdx.x * WAVES_PER_BLOCK_ + wave;   // 0..15999
  const int b = row / NS_;
  const int n = row - b * NS_;

  const float* __restrict__ xr = x + (size_t)b * D_;
  const float* __restrict__ nr = noise + ((size_t)b * NS_ + n) * D_;
  const int base_i = lane * PER_LANE_;

  float p[PER_LANE_];
#pragma unroll
  for (int j = 0; j < PER_LANE_; j += 4) {
    const float4 nv = *reinterpret_cast<const float4*>(nr + base_i + j);
    const float4 xv = *reinterpret_cast<const float4*>(xr + base_i + j);
    p[j + 0] = fmaf(SIGMA_, nv.x, xv.x);
    p[j + 1] = fmaf(SIGMA_, nv.y, xv.y);
    p[j + 2] = fmaf(SIGMA_, nv.z, xv.z);
    p[j + 3] = fmaf(SIGMA_, nv.w, xv.w);
  }

  const float cf = cutf[b];   // wave-uniform

  // candidate mask in float domain (monotone-equivalent to key >= order_key(cf))
  uint32_t m = 0;
#pragma unroll
  for (int j = 0; j < PER_LANE_; ++j) m |= (p[j] >= cf) ? (1u << j) : 0u;
  const int cnt = __popc(m);

  // ballot-based exclusive scan of cnt (6 bits) -> offset, and total C
  const uint64_t below = (lane == 0) ? 0ull : ((~0ull) >> (64 - lane));
  int offset = 0, C = 0;
#pragma unroll
  for (int t = 0; t < 6; ++t) {
    const uint64_t mb = __ballot((cnt >> t) & 1);
    offset += (int)__popcll(mb & below) << t;
    C      += (int)__popcll(mb) << t;
  }

  float* __restrict__ idx_row = out_idx + (size_t)row * TOPK_;

  if (C >= TOPK_ && C <= CAP_) {
    // ---------- fast path ----------
    {
      uint32_t mm = m; int q = offset;
      while (mm) {
        const int j = __ffs(mm) - 1; mm &= mm - 1;
        comp[wave][q] = make_uint2(order_key(p[j]), (uint32_t)(base_i + j));
        ++q;
      }
    }
    __asm__ volatile("s_waitcnt lgkmcnt(0)" ::: "memory");

    uint32_t kk[SLOTS_], ki[SLOTS_];
    bool valid[SLOTS_];
#pragma unroll
    for (int s = 0; s < SLOTS_; ++s) {
      const int q = (s << 6) + lane;
      valid[s] = (q < C);
      const uint2 v = valid[s] ? comp[wave][q] : make_uint2(0u, 0u);
      kk[s] = v.x; ki[s] = v.y;   // pad key 0 never matches a radix class
    }

    // common-prefix skip: and/or reduce over candidate keys
    uint32_t orv = 0u, andv = 0xFFFFFFFFu;
#pragma unroll
    for (int s = 0; s < SLOTS_; ++s) {
      orv  |= valid[s] ? kk[s] : 0u;
      andv &= valid[s] ? kk[s] : 0xFFFFFFFFu;
    }
#pragma unroll
    for (int off = 32; off >= 1; off >>= 1) {
      orv  |= __shfl_xor(orv, off);
      andv &= __shfl_xor(andv, off);
    }
    const uint32_t diff = orv ^ andv;

    uint32_t prefix; int r;
    if (diff == 0u) {
      // all candidate keys identical (degenerate): kth is that key
      prefix = orv; r = TOPK_;
    } else {
      const int startbit = 31 - __clz(diff);
      prefix = (startbit == 31) ? 0u : (andv & (0xFFFFFFFFu << (startbit + 1)));
      int k = TOPK_;
      int A = C;   // keys matching prefix in bits above startbit
#pragma unroll 1
      for (int bit = startbit; bit >= 0; --bit) {
        const uint32_t want = (prefix >> bit) | 1u;
        int c = 0;
#pragma unroll
        for (int s = 0; s < SLOTS_; ++s)
          c += __popcll(__ballot((kk[s] >> bit) == want));
        if (c >= k) { prefix |= (1u << bit); A = c; }
        else        { k -= c; A -= c; }
        if (A == 1) {
          // unique survivor: it IS the kth-largest (k==1). broadcast its key.
          uint32_t mykey = 0u; bool have = false;
#pragma unroll
          for (int s = 0; s < SLOTS_; ++s) {
            const bool hit = valid[s] && ((kk[s] >> bit) == (prefix >> bit));
            mykey = hit ? kk[s] : mykey;
            have |= hit;
          }
          const uint64_t mb = __ballot(have);
          const int src = __ffsll((unsigned long long)mb) - 1;
          prefix = __shfl(mykey, src);
          k = 1;
          break;
        }
      }
      r = k;
    }

    // ballot-ranked emission, ascending index order
    int sel_run = 0, eq_run = 0;
#pragma unroll
    for (int s = 0; s < SLOTS_; ++s) {
      const bool gt = kk[s] > prefix;
      const bool eq = kk[s] == prefix;
      const uint64_t meq = __ballot(eq);
      const int eqrank = eq_run + __popcll(meq & below);
      const bool sel = gt || (eq && (eqrank < r));
      const uint64_t msel = __ballot(sel);
      if (sel) {
        const int pos = sel_run + __popcll(msel & below);
        idx_row[pos] = (float)(int)ki[s];
      }
      sel_run += __popcll(msel);
      eq_run  += __popcll(meq);
    }
  } else {
    // ---------- fallback (rare): exact select over all 2048 ----------
    uint32_t keys[PER_LANE_];
#pragma unroll
    for (int j = 0; j < PER_LANE_; ++j) keys[j] = order_key(p[j]);

    uint32_t prefix = 0; int k = TOPK_;
#pragma unroll 1
    for (int bit = 31; bit >= 0; --bit) {
      const uint32_t want = (prefix >> bit) | 1u;
      int c = 0;
#pragma unroll
      for (int j = 0; j < PER_LANE_; ++j) c += ((keys[j] >> bit) == want) ? 1 : 0;
#pragma unroll
      for (int off = 32; off >= 1; off >>= 1) c += __shfl_xor(c, off);
      if (c >= k) prefix |= (1u << bit); else k -= c;
    }
    const int r = k;

    int gt = 0, eq = 0;
#pragma unroll
    for (int j = 0; j < PER_LANE_; ++j) {
      gt += (keys[j] > prefix) ? 1 : 0;
      eq += (keys[j] == prefix) ? 1 : 0;
    }
    uint32_t incl2 = (uint32_t)gt | ((uint32_t)eq << 16);
#pragma unroll
    for (int off = 1; off < 64; off <<= 1) {
      uint32_t y = __shfl_up(incl2, (unsigned)off);
      if (lane >= off) incl2 += y;
    }
    const int gt_base = (int)(incl2 & 0xFFFFu) - gt;
    const int eq_base = (int)(incl2 >> 16) - eq;
    int pos = gt_base + min(eq_base, r);
    int eq_seen = eq_base;
#pragma unroll
    for (int j = 0; j < PER_LANE_; ++j) {
      const uint32_t kj = keys[j];
      bool s = false;
      if (kj > prefix) s = true;
      else if (kj == prefix) { s = (eq_seen < r); eq_seen++; }
      if (s) { idx_row[pos] = (float)(base_i + j); pos++; }
    }
  }
}

// ---- kernel 3: histograms -> indicators (writes every element; no memset) ----
__global__ __launch_bounds__(256) void ptk_hist(
    const float* __restrict__ out_idx, float* __restrict__ indicators) {
  __shared__ int hist[JCHUNK_][D_];   // 64 KB

  const int tid   = threadIdx.x;
  const int b     = blockIdx.x >> 4;         // 16 chunks per b
  const int chunk = blockIdx.x & 15;
  const int j0    = chunk * JCHUNK_;

  int4* h4 = (int4*)hist;
  for (int t = tid; t < JCHUNK_ * D_ / 4; t += 256)
    h4[t] = make_int4(0, 0, 0, 0);
  __syncthreads();

  const float* __restrict__ src = out_idx + (size_t)b * NS_ * TOPK_ + j0;
  for (int t = tid; t < NS_ * 2; t += 256) {     // 2 float4 per sample (8 ranks)
    const int n = t >> 1;
    const int q = (t & 1) << 2;
    const float4 v = *reinterpret_cast<const float4*>(src + (size_t)n * TOPK_ + q);
    atomicAdd(&hist[q + 0][(int)v.x], 1);
    atomicAdd(&hist[q + 1][(int)v.y], 1);
    atomicAdd(&hist[q + 2][(int)v.z], 1);
    atomicAdd(&hist[q + 3][(int)v.w], 1);
  }
  __syncthreads();

  float4* __restrict__ dst =
      (float4*)(indicators + ((size_t)b * TOPK_ + j0) * D_);
  for (int t = tid; t < JCHUNK_ * D_ / 4; t += 256) {
    const int4 h = h4[t];
    float4 o;
    o.x = (float)h.x / (float)NS_;
    o.y = (float)h.y / (float)NS_;
    o.z = (float)h.z / (float)NS_;
    o.w = (float)h.w / (float)NS_;
    dst[t] = o;
  }
}

extern "C" void kernel_launch(void* const* d_in, const int* in_sizes, int n_in,
                              void* d_out, int out_size, void* d_ws, size_t ws_size,
                              hipStream_t stream) {
  const float* x     = (const float*)d_in[0];
  const float* noise = (const float*)d_in[1];
  float* indicators  = (float*)d_out;
  float* out_idx     = (float*)d_out + (size_t)B_ * TOPK_ * D_;
  float* cutf        = (float*)d_ws;

  hipLaunchKernelGGL(ptk_cutoff, dim3(B_), dim3(64), 0, stream, x, cutf);

  const int rows = B_ * NS_;                        // 16000
  hipLaunchKernelGGL(ptk_select, dim3(rows / WAVES_PER_BLOCK_), dim3(256), 0,
                     stream, x, noise, cutf, out_idx);

  hipLaunchKernelGGL(ptk_hist, dim3(B_ * 16), dim3(256), 0, stream,
                     out_idx, indicators);
}